// Round 3
// baseline (17608.621 us; speedup 1.0000x reference)
//
#include <hip/hip_runtime.h>

// ManualLSTM: B=32, S=2048, I=256, H=512. Persistent kernel, 64 WGs x 256 thr.
// Round-5: r3's dataflow-tagged spin + SELECTIVE PER-CHUNK RELOAD.
//   History: r2 (flags+agent loads) 13.9ms. r3 (tagged spin, full reload) PASSED
//   but 16.8ms -- every retry re-issued all 32 chunks + vmcnt(0) on all (64-WG
//   storm, FETCH 593MB->1.37GB). r4 (XCD leader staging) FAILED correctness:
//   sc0 member loads can be served from the member CU's stale L1 (sc0/sc1 are
//   scope bits; no verified "bypass L1, hit local L2" encoding) -- abandoned.
//   v5 = r3 verbatim, except the spin tracks staleness per 16B chunk (32-bit
//   mask) and retries reload ONLY chunks where __any(lane stale) -- a wave-
//   uniform branch. Stale chunks cluster by straggler producer WG (chunk pair
//   ks = g>>2 for lanes lq = g&3), so a one-WG tail re-pulls 2 chunks, not 32.
//   Protocol (unchanged, correctness-proven in r3):
//   * h published as (tag<<16)|bf16(h) u32 words, 8B stores, sc0 sc1.
//   * producer of step t writes slot t&1 with tag t+1; consumer of step t
//     reads slot (t+1)&1 expecting tag t. Publishing t+1 requires having
//     consumed all tag-t words -> every WG consumed h_{t-1} before its slot is
//     overwritten (covers slot WAR and gat WAR; one __syncthreads per step).
//   * W_hh fragments in VGPRs; W_ih in LDS (x-part off-path); x_{t+1}
//     prefetched under the h-MFMA chain.

#define BB 32
#define SS 2048
#define II 256
#define HH 512
#define GG 64
#define NT 256
#define SLOT (BB * HH)   // 16384 words per h slot

typedef __bf16 bf16x8 __attribute__((ext_vector_type(8)));
typedef float f32x4 __attribute__((ext_vector_type(4)));
typedef unsigned u32x4 __attribute__((ext_vector_type(4)));
typedef unsigned u32x2 __attribute__((ext_vector_type(2)));

union BFU { __bf16 h; unsigned short u; };
union FRG { unsigned d[4]; bf16x8 b; };

__device__ __forceinline__ bf16x8 cvt8(float4 a, float4 b) {
  bf16x8 r;
  r[0] = (__bf16)a.x; r[1] = (__bf16)a.y; r[2] = (__bf16)a.z; r[3] = (__bf16)a.w;
  r[4] = (__bf16)b.x; r[5] = (__bf16)b.y; r[6] = (__bf16)b.z; r[7] = (__bf16)b.w;
  return r;
}

__global__ __launch_bounds__(256, 1) void lstm_init(
    const float* __restrict__ h0, unsigned* __restrict__ hw) {
  int i = blockIdx.x * 256 + threadIdx.x;   // 0..16383 = B*H
  BFU cv; cv.h = (__bf16)h0[i];
  hw[SLOT + i] = (unsigned)cv.u;   // slot 1: tag 0 | bf16(h0)  (t=0 reads this)
  hw[i] = 0xFFFF0000u;             // slot 0: sentinel tag (ws is re-poisoned)
}

__global__ __launch_bounds__(256, 1) void lstm_persistent(
    const float* __restrict__ x, const float* __restrict__ c0,
    const float* __restrict__ W_ih, const float* __restrict__ b_ih,
    const float* __restrict__ W_hh, float* __restrict__ out,
    unsigned* __restrict__ hw) {
  __shared__ __bf16 Wi[32][264];   // x-part weights (row pad: 528B, 16B-aligned)
  __shared__ float gat[32][41];    // gates tile

  const int g = blockIdx.x;
  const int tid = threadIdx.x;

  // ---- stage W_ih slice into LDS as bf16 (once) ----
  for (int i = tid; i < 32 * II; i += NT) {
    const int r = i >> 8, k = i & 255;
    const int grow = (r >> 3) * HH + g * 8 + (r & 7);
    Wi[r][k] = (__bf16)W_ih[(size_t)grow * II + k];
  }

  // ---- MFMA mapping (M=32 batches, N=32 local gate cols) ----
  const int wave = tid >> 6;
  const int lane = tid & 63;
  const int lm = lane & 15;
  const int lq = lane >> 4;
  const int mtile = wave & 1;
  const int ntile = wave >> 1;
  const int am = mtile * 16 + lm;   // A row (batch)
  const int bn = ntile * 16 + lm;   // B row (local gate col)

  // ---- W_hh fragments -> registers, bf16 (16 x bf16x8 = 64 VGPR/lane) ----
  const int growb = (bn >> 3) * HH + g * 8 + (bn & 7);
  const float* whr = W_hh + (size_t)growb * HH + lq * 8;
#define WLD(N) const bf16x8 wb##N = \
  cvt8(*(const float4*)(whr + N * 32), *(const float4*)(whr + N * 32 + 4));
  WLD(0)  WLD(1)  WLD(2)  WLD(3)  WLD(4)  WLD(5)  WLD(6)  WLD(7)
  WLD(8)  WLD(9)  WLD(10) WLD(11) WLD(12) WLD(13) WLD(14) WLD(15)
#undef WLD

  // ---- cell mapping: 128 threads x 2 cells ----
  const int eb = tid >> 2;              // batch (valid for tid<128)
  const int cp = (tid & 3) * 2;         // even h-col within this WG's 8
  const int colg = g * 8 + cp;
  float2 cc = make_float2(0.f, 0.f), hl = make_float2(0.f, 0.f);
  float2 bI = {}, bF = {}, bG = {}, bO = {};
  if (tid < 128) {
    bI = *(const float2*)(b_ih + 0 * HH + colg);
    bF = *(const float2*)(b_ih + 1 * HH + colg);
    bG = *(const float2*)(b_ih + 2 * HH + colg);
    bO = *(const float2*)(b_ih + 3 * HH + colg);
    cc = *(const float2*)(c0 + eb * HH + colg);
  }

  const float* xrow = x + (size_t)am * (SS * II);
  const unsigned* hbE = hw + SLOT + am * HH + lq * 8;  // even t: read slot 1
  const unsigned* hbO = hw + am * HH + lq * 8;         // odd  t: read slot 0
  unsigned* pbE = hw + eb * HH + colg;                 // even t: write slot 0
  unsigned* pbO = hw + SLOT + eb * HH + colg;          // odd  t: write slot 1

  // ---- x fragment prefetch for t=0 ----
  bf16x8 xf0, xf1, xf2, xf3, xf4, xf5, xf6, xf7;
#define XPF(T) { const float* xt_ = xrow + (size_t)(T) * II + lq * 8; \
  xf0 = cvt8(*(const float4*)(xt_ + 0),   *(const float4*)(xt_ + 4));   \
  xf1 = cvt8(*(const float4*)(xt_ + 32),  *(const float4*)(xt_ + 36));  \
  xf2 = cvt8(*(const float4*)(xt_ + 64),  *(const float4*)(xt_ + 68));  \
  xf3 = cvt8(*(const float4*)(xt_ + 96),  *(const float4*)(xt_ + 100)); \
  xf4 = cvt8(*(const float4*)(xt_ + 128), *(const float4*)(xt_ + 132)); \
  xf5 = cvt8(*(const float4*)(xt_ + 160), *(const float4*)(xt_ + 164)); \
  xf6 = cvt8(*(const float4*)(xt_ + 192), *(const float4*)(xt_ + 196)); \
  xf7 = cvt8(*(const float4*)(xt_ + 224), *(const float4*)(xt_ + 228)); }
  XPF(0)

  __syncthreads();

#define LDC(Q, OFF) asm volatile( \
  "global_load_dwordx4 %0, %1, off offset:" #OFF " sc0 sc1" \
  : "=v"(Q) : "v"(hb) : "memory");
#define LDALL() { \
  LDC(q0, 0)     LDC(q1, 16)    LDC(q2, 128)   LDC(q3, 144)  \
  LDC(q4, 256)   LDC(q5, 272)   LDC(q6, 384)   LDC(q7, 400)  \
  LDC(q8, 512)   LDC(q9, 528)   LDC(q10, 640)  LDC(q11, 656) \
  LDC(q12, 768)  LDC(q13, 784)  LDC(q14, 896)  LDC(q15, 912) \
  LDC(q16, 1024) LDC(q17, 1040) LDC(q18, 1152) LDC(q19, 1168) \
  LDC(q20, 1280) LDC(q21, 1296) LDC(q22, 1408) LDC(q23, 1424) \
  LDC(q24, 1536) LDC(q25, 1552) LDC(q26, 1664) LDC(q27, 1680) \
  LDC(q28, 1792) LDC(q29, 1808) LDC(q30, 1920) LDC(q31, 1936) }
// per-chunk staleness bit (tags ride in .x/.z high halves of each 16B chunk)
#define CK(Q, BIT) { if (((Q.x ^ etag) | (Q.z ^ etag)) & 0xFFFF0000u) \
  st |= BIT##u; }
// selective reload: wave-uniform branch, reload chunk iff ANY lane stale
#define RLD(Q, OFF, BIT) if (__any((int)(st & BIT##u))) { asm volatile( \
  "global_load_dwordx4 %0, %1, off offset:" #OFF " sc0 sc1" \
  : "=v"(Q) : "v"(hb) : "memory"); }
#define XMF(N) { const bf16x8 wib = *(const bf16x8*)(&Wi[bn][N * 32 + lq * 8]); \
  accA = __builtin_amdgcn_mfma_f32_16x16x32_bf16(xf##N, wib, accA, 0, 0, 0); }
#define HMF(QA, QB, WN, ACC) { FRG u_; \
  u_.d[0] = __builtin_amdgcn_perm(QA.y, QA.x, 0x05040100u); \
  u_.d[1] = __builtin_amdgcn_perm(QA.w, QA.z, 0x05040100u); \
  u_.d[2] = __builtin_amdgcn_perm(QB.y, QB.x, 0x05040100u); \
  u_.d[3] = __builtin_amdgcn_perm(QB.w, QB.z, 0x05040100u); \
  ACC = __builtin_amdgcn_mfma_f32_16x16x32_bf16(u_.b, WN, ACC, 0, 0, 0); }

  for (int t = 0; t < SS; ++t) {
    const unsigned etag = ((unsigned)t) << 16;
    const unsigned* hb = (t & 1) ? hbO : hbE;
    u32x4 q0, q1, q2, q3, q4, q5, q6, q7, q8, q9, q10, q11, q12, q13, q14, q15,
          q16, q17, q18, q19, q20, q21, q22, q23, q24, q25, q26, q27, q28, q29,
          q30, q31;

    // ---- 1. speculative h loads: issued first, fly during the x-part ----
    LDALL();

    // ---- 2. x-part: LDS + register operands only, no global waits ----
    f32x4 accA = {0.f, 0.f, 0.f, 0.f};
    f32x4 accB = {0.f, 0.f, 0.f, 0.f};
    XMF(0) XMF(1) XMF(2) XMF(3) XMF(4) XMF(5) XMF(6) XMF(7)

    // ---- 3. spin on the data's own tags, selective per-chunk reload ----
    for (;;) {
      asm volatile("s_waitcnt vmcnt(0)" ::: "memory");
      __builtin_amdgcn_sched_barrier(0);
      unsigned st = 0u;
      CK(q0, 0x1)        CK(q1, 0x2)        CK(q2, 0x4)        CK(q3, 0x8)
      CK(q4, 0x10)       CK(q5, 0x20)       CK(q6, 0x40)       CK(q7, 0x80)
      CK(q8, 0x100)      CK(q9, 0x200)      CK(q10, 0x400)     CK(q11, 0x800)
      CK(q12, 0x1000)    CK(q13, 0x2000)    CK(q14, 0x4000)    CK(q15, 0x8000)
      CK(q16, 0x10000)   CK(q17, 0x20000)   CK(q18, 0x40000)   CK(q19, 0x80000)
      CK(q20, 0x100000)  CK(q21, 0x200000)  CK(q22, 0x400000)  CK(q23, 0x800000)
      CK(q24, 0x1000000) CK(q25, 0x2000000) CK(q26, 0x4000000) CK(q27, 0x8000000)
      CK(q28, 0x10000000) CK(q29, 0x20000000) CK(q30, 0x40000000)
      CK(q31, 0x80000000)
      if (__all((int)(st == 0u))) break;
      RLD(q0, 0, 0x1)          RLD(q1, 16, 0x2)
      RLD(q2, 128, 0x4)        RLD(q3, 144, 0x8)
      RLD(q4, 256, 0x10)       RLD(q5, 272, 0x20)
      RLD(q6, 384, 0x40)       RLD(q7, 400, 0x80)
      RLD(q8, 512, 0x100)      RLD(q9, 528, 0x200)
      RLD(q10, 640, 0x400)     RLD(q11, 656, 0x800)
      RLD(q12, 768, 0x1000)    RLD(q13, 784, 0x2000)
      RLD(q14, 896, 0x4000)    RLD(q15, 912, 0x8000)
      RLD(q16, 1024, 0x10000)  RLD(q17, 1040, 0x20000)
      RLD(q18, 1152, 0x40000)  RLD(q19, 1168, 0x80000)
      RLD(q20, 1280, 0x100000) RLD(q21, 1296, 0x200000)
      RLD(q22, 1408, 0x400000) RLD(q23, 1424, 0x800000)
      RLD(q24, 1536, 0x1000000)  RLD(q25, 1552, 0x2000000)
      RLD(q26, 1664, 0x4000000)  RLD(q27, 1680, 0x8000000)
      RLD(q28, 1792, 0x10000000) RLD(q29, 1808, 0x20000000)
      RLD(q30, 1920, 0x40000000) RLD(q31, 1936, 0x80000000)
    }

    // ---- 4. x prefetch for t+1: latency hides under the h-MFMA chain ----
    { const int tn = (t < SS - 1) ? t + 1 : t; XPF(tn) }

    // ---- 5. h-part: extract (v_perm) + MFMA, two independent acc chains ----
    HMF(q0, q1, wb0, accB)    HMF(q2, q3, wb1, accA)
    HMF(q4, q5, wb2, accB)    HMF(q6, q7, wb3, accA)
    HMF(q8, q9, wb4, accB)    HMF(q10, q11, wb5, accA)
    HMF(q12, q13, wb6, accB)  HMF(q14, q15, wb7, accA)
    HMF(q16, q17, wb8, accB)  HMF(q18, q19, wb9, accA)
    HMF(q20, q21, wb10, accB) HMF(q22, q23, wb11, accA)
    HMF(q24, q25, wb12, accB) HMF(q26, q27, wb13, accA)
    HMF(q28, q29, wb14, accB) HMF(q30, q31, wb15, accA)

    // D layout: col = lane&15, row = (lane>>4)*4 + r (m89-verified)
#pragma unroll
    for (int r = 0; r < 4; ++r)
      gat[mtile * 16 + lq * 4 + r][ntile * 16 + lm] = accA[r] + accB[r];
    __syncthreads();

    // ---- 6. cell math (128 threads x 2 cells) + tagged 8B publish ----
    if (tid < 128) {
      float hv0, hv1;
      unsigned pw0, pw1;
      const unsigned th = ((unsigned)(t + 1)) << 16;
      {
        float iv = gat[eb][cp]      + bI.x;
        float fv = gat[eb][8 + cp]  + bF.x;
        float gv = gat[eb][16 + cp] + bG.x;
        float o  = gat[eb][24 + cp] + bO.x;
        iv = 1.f / (1.f + __expf(-iv));
        fv = 1.f / (1.f + __expf(-fv));
        o  = 1.f / (1.f + __expf(-o));
        gv = 2.f / (1.f + __expf(-2.f * gv)) - 1.f;
        cc.x = fv * cc.x + iv * gv;
        const float thh = 2.f / (1.f + __expf(-2.f * cc.x)) - 1.f;
        hv0 = o * thh;
        BFU b_; b_.h = (__bf16)hv0;
        pw0 = th | (unsigned)b_.u;
      }
      {
        float iv = gat[eb][cp + 1]      + bI.y;
        float fv = gat[eb][8 + cp + 1]  + bF.y;
        float gv = gat[eb][16 + cp + 1] + bG.y;
        float o  = gat[eb][24 + cp + 1] + bO.y;
        iv = 1.f / (1.f + __expf(-iv));
        fv = 1.f / (1.f + __expf(-fv));
        o  = 1.f / (1.f + __expf(-o));
        gv = 2.f / (1.f + __expf(-2.f * gv)) - 1.f;
        cc.y = fv * cc.y + iv * gv;
        const float thh = 2.f / (1.f + __expf(-2.f * cc.y)) - 1.f;
        hv1 = o * thh;
        BFU b_; b_.h = (__bf16)hv1;
        pw1 = th | (unsigned)b_.u;
      }
      hl.x = hv0; hl.y = hv1;
      u32x2 pv; pv.x = pw0; pv.y = pw1;
      unsigned* pb = (t & 1) ? pbO : pbE;
      asm volatile("global_store_dwordx2 %0, %1, off sc0 sc1"
                   :: "v"(pb), "v"(pv) : "memory");
      // out[] store after publish: off the critical path, plain cached store
      float2 ov; ov.x = hv0; ov.y = hv1;
      *(float2*)(out + (size_t)eb * (SS * HH) + (size_t)t * HH + colg) = ov;
    }
  }

  // ---- final h, c ----
  if (tid < 128) {
    const size_t OUTH = (size_t)BB * SS * HH;
    *(float2*)(out + OUTH + eb * HH + colg) = hl;
    *(float2*)(out + OUTH + BB * HH + eb * HH + colg) = cc;
  }
}

extern "C" void kernel_launch(void* const* d_in, const int* in_sizes, int n_in,
                              void* d_out, int out_size, void* d_ws, size_t ws_size,
                              hipStream_t stream) {
  const float* x    = (const float*)d_in[0];
  const float* h0   = (const float*)d_in[1];
  const float* c0   = (const float*)d_in[2];
  const float* W_ih = (const float*)d_in[3];
  const float* b_ih = (const float*)d_in[4];
  const float* W_hh = (const float*)d_in[5];
  float* out = (float*)d_out;

  // ws layout: tagged h words, 2 slots x 32x512 u32 = 128KB. No flags.
  unsigned* hw = (unsigned*)d_ws;

  lstm_init<<<64, 256, 0, stream>>>(h0, hw);
  lstm_persistent<<<GG, 256, 0, stream>>>(x, c0, W_ih, b_ih, W_hh, out, hw);
}

// Round 4
// 7461.197 us; speedup vs baseline: 2.3600x; 2.3600x over previous
//
#include <hip/hip_runtime.h>

// ManualLSTM: B=32, S=2048, I=256, H=512.
// Round-6: BATCH-GROUPED EXCHANGE. The recurrence is independent per batch
// element, so split batches into 2 groups of 16; each group's 16 WGs hold the
// FULL W_hh in registers (128 VGPR/thread) and exchange h ONLY within the
// group (fan 16, payload 32KB/WG/step) instead of the old all-to-all
// (fan 64, 2MB/step + flag polls) that dominated r2/r3/r5 (13.9-17.6ms).
//   * Grid 32 WGs x 256 thr. WG (grp, j): batches 16*grp..+15, h-cols
//     32*j..+31 (N=128 gate rows). K is split across the WG's 4 waves
//     (h: 128 K each, x: 64 K each); per-wave partial sums reduce via LDS.
//   * Exchange: r3's correctness-proven tagged-word protocol, group-local.
//     h words = (tag<<16)|bf16(h), 8B stores sc0 sc1; producer of step t
//     writes slot (t+1)&1 tag t+1; consumer of step t reads slot t&1 tag t.
//     Publish-certifies-consumption induction covers slot WAR; two
//     __syncthreads per step cover the LDS partial-tile WAR.
//   * Peers publish and pull nearly simultaneously (symmetric), so the first
//     speculative pull catches most chunks; selective per-chunk reload for
//     stragglers. x-part MFMA and x_{t+1} prefetch overlap pull latency.

#define BB 32
#define SS 2048
#define II 256
#define HH 512
#define NT 256
#define SLOTW 8192              // words per group-slot: 16 batches x 512 cols

typedef __bf16 bf16x8 __attribute__((ext_vector_type(8)));
typedef float f32x4 __attribute__((ext_vector_type(4)));
typedef unsigned u32x4 __attribute__((ext_vector_type(4)));
typedef unsigned u32x2 __attribute__((ext_vector_type(2)));

union BFU { __bf16 h; unsigned short u; };
union FRG { unsigned d[4]; bf16x8 b; };

__device__ __forceinline__ bf16x8 cvt8(float4 a, float4 b) {
  bf16x8 r;
  r[0] = (__bf16)a.x; r[1] = (__bf16)a.y; r[2] = (__bf16)a.z; r[3] = (__bf16)a.w;
  r[4] = (__bf16)b.x; r[5] = (__bf16)b.y; r[6] = (__bf16)b.z; r[7] = (__bf16)b.w;
  return r;
}

__global__ __launch_bounds__(256, 1) void lstm_init(
    const float* __restrict__ h0, unsigned* __restrict__ hw) {
  int i = blockIdx.x * 256 + threadIdx.x;   // 0..16383 = B*H
  const int b = i >> 9, col = i & 511;
  const int G = b >> 4, bl = b & 15;
  BFU cv; cv.h = (__bf16)h0[i];
  hw[(G * 2 + 0) * SLOTW + bl * 512 + col] = (unsigned)cv.u;  // slot0: tag 0|h0
  hw[(G * 2 + 1) * SLOTW + bl * 512 + col] = 0xFFFF0000u;     // slot1: sentinel
}

__global__ __launch_bounds__(256, 1) void lstm_persistent(
    const float* __restrict__ x, const float* __restrict__ c0,
    const float* __restrict__ W_ih, const float* __restrict__ b_ih,
    const float* __restrict__ W_hh, float* __restrict__ out,
    unsigned* __restrict__ hw) {
  __shared__ __bf16 Wi[128][264];      // x-part weights: N=128 rows x 256 K
  __shared__ float pgat[4][16][132];   // per-wave partial gates (pad 132)

  const int g = blockIdx.x;
  const int wgj = g & 15;              // col-slice within group
  const int grp = g >> 4;              // batch group (0/1)
  const int tid = threadIdx.x;
  const int wave = tid >> 6;
  const int lane = tid & 63;
  const int lm = lane & 15;            // batch row (M) / gate-col row (N)
  const int lq = lane >> 4;            // k-quarter within a 32-K tile

  // ---- stage W_ih slice into LDS as bf16 (once) ----
  for (int i = tid; i < 128 * II; i += NT) {
    const int row = i >> 8, k = i & 255;
    const int grow = (row >> 5) * HH + wgj * 32 + (row & 31);
    Wi[row][k] = (__bf16)W_ih[(size_t)grow * II + k];
  }

  // ---- W_hh fragments -> registers: wb[n][kt], n=8 N-tiles, kt=4 K-tiles
  //      (this wave's K-range: [wave*128, wave*128+128)) = 128 VGPR ----
  bf16x8 wb[8][4];
#pragma unroll
  for (int n = 0; n < 8; ++n) {
    const int localN = n * 16 + lm;
    const int grow = (localN >> 5) * HH + wgj * 32 + (localN & 31);
    const float* whr = W_hh + (size_t)grow * HH + wave * 128 + lq * 8;
#pragma unroll
    for (int kt = 0; kt < 4; ++kt)
      wb[n][kt] = cvt8(*(const float4*)(whr + kt * 32),
                       *(const float4*)(whr + kt * 32 + 4));
  }

  // ---- cell mapping: 256 threads x 2 cells (16 batches x 32 cols) ----
  const int bl = tid >> 4;             // local batch 0..15
  const int cpl = (tid & 15) * 2;      // even local h-col 0..30
  const int gb = grp * 16 + bl;        // global batch
  const int gcol = wgj * 32 + cpl;     // global h-col
  float2 cc, hl = make_float2(0.f, 0.f);
  float2 bI = *(const float2*)(b_ih + 0 * HH + gcol);
  float2 bF = *(const float2*)(b_ih + 1 * HH + gcol);
  float2 bG = *(const float2*)(b_ih + 2 * HH + gcol);
  float2 bO = *(const float2*)(b_ih + 3 * HH + gcol);
  cc = *(const float2*)(c0 + gb * HH + gcol);

  // ---- pointers ----
  unsigned* grpb = hw + grp * 2 * SLOTW;
  // pull base (this wave's K-quarter of the group payload), byte address
  const char* pl0 = (const char*)(grpb + lm * 512 + wave * 128 + lq * 8);
  const char* pl1 = (const char*)(grpb + SLOTW + lm * 512 + wave * 128 + lq * 8);
  // publish base (this thread's 2 cells)
  unsigned* pub0 = grpb + bl * 512 + gcol;
  unsigned* pub1 = grpb + SLOTW + bl * 512 + gcol;
  const float* xrow = x + (size_t)(grp * 16 + lm) * (SS * II) + wave * 64 + lq * 8;

  // ---- x fragment prefetch for t=0 (this wave's 64-K slice) ----
  bf16x8 xa0, xa1;
#define XPF(T) { const float* xt_ = xrow + (size_t)(T) * II; \
  xa0 = cvt8(*(const float4*)(xt_),      *(const float4*)(xt_ + 4));  \
  xa1 = cvt8(*(const float4*)(xt_ + 32), *(const float4*)(xt_ + 36)); }
  XPF(0)

  __syncthreads();

#define LDC(Q, OFF) asm volatile( \
  "global_load_dwordx4 %0, %1, off offset:" #OFF " sc0 sc1" \
  : "=v"(Q) : "v"(pb) : "memory");
#define CK(Q, BIT) { if (((Q.x ^ etag) | (Q.z ^ etag)) & 0xFFFF0000u) \
  st |= BIT##u; }
#define RLD(Q, OFF, BIT) if (__any((int)(st & BIT##u))) { asm volatile( \
  "global_load_dwordx4 %0, %1, off offset:" #OFF " sc0 sc1" \
  : "=v"(Q) : "v"(pb) : "memory"); }
// A-fragment from two tagged chunks (8 cols) + 8 MFMAs into all N-tiles
#define HSTEP(QA, QB, KT) { FRG u_; \
  u_.d[0] = __builtin_amdgcn_perm(QA.y, QA.x, 0x05040100u); \
  u_.d[1] = __builtin_amdgcn_perm(QA.w, QA.z, 0x05040100u); \
  u_.d[2] = __builtin_amdgcn_perm(QB.y, QB.x, 0x05040100u); \
  u_.d[3] = __builtin_amdgcn_perm(QB.w, QB.z, 0x05040100u); \
  _Pragma("unroll") \
  for (int n = 0; n < 8; ++n) \
    acc[n] = __builtin_amdgcn_mfma_f32_16x16x32_bf16(u_.b, wb[n][KT], \
                                                     acc[n], 0, 0, 0); }

  for (int t = 0; t < SS; ++t) {
    const unsigned etag = ((unsigned)t) << 16;
    const char* pb = (t & 1) ? pl1 : pl0;
    u32x4 q0, q1, q2, q3, q4, q5, q6, q7;

    // ---- 1. speculative pulls of this wave's K-quarter (8 x 16B) ----
    LDC(q0, 0)   LDC(q1, 16)  LDC(q2, 128) LDC(q3, 144)
    LDC(q4, 256) LDC(q5, 272) LDC(q6, 384) LDC(q7, 400)

    // ---- 2. x-part (overlaps pull flight): LDS weights, reg x-frags ----
    f32x4 acc[8] = {};
#pragma unroll
    for (int n = 0; n < 8; ++n) {
      const bf16x8 wib = *(const bf16x8*)(&Wi[n * 16 + lm][wave * 64 + lq * 8]);
      acc[n] = __builtin_amdgcn_mfma_f32_16x16x32_bf16(xa0, wib, acc[n], 0, 0, 0);
    }
#pragma unroll
    for (int n = 0; n < 8; ++n) {
      const bf16x8 wib =
          *(const bf16x8*)(&Wi[n * 16 + lm][wave * 64 + 32 + lq * 8]);
      acc[n] = __builtin_amdgcn_mfma_f32_16x16x32_bf16(xa1, wib, acc[n], 0, 0, 0);
    }

    // ---- 3. spin on data tags, selective per-chunk reload (fan = 16) ----
    for (;;) {
      asm volatile("s_waitcnt vmcnt(0)" ::: "memory");
      __builtin_amdgcn_sched_barrier(0);
      unsigned st = 0u;
      CK(q0, 0x1)  CK(q1, 0x2)  CK(q2, 0x4)  CK(q3, 0x8)
      CK(q4, 0x10) CK(q5, 0x20) CK(q6, 0x40) CK(q7, 0x80)
      if (__all((int)(st == 0u))) break;
      RLD(q0, 0, 0x1)    RLD(q1, 16, 0x2)
      RLD(q2, 128, 0x4)  RLD(q3, 144, 0x8)
      RLD(q4, 256, 0x10) RLD(q5, 272, 0x20)
      RLD(q6, 384, 0x40) RLD(q7, 400, 0x80)
    }

    // ---- 4. x prefetch for t+1 (hides under h-MFMA chain) ----
    { const int tn = (t < SS - 1) ? t + 1 : t; XPF(tn) }

    // ---- 5. h-part: 4 K-tiles x 8 N-tiles of MFMA ----
    HSTEP(q0, q1, 0) HSTEP(q2, q3, 1) HSTEP(q4, q5, 2) HSTEP(q6, q7, 3)

    // ---- 6. per-wave partial gates -> LDS; reduce after barrier ----
    // D layout: col = lane&15 (N within tile), row = lq*4 + r (M) [m89]
#pragma unroll
    for (int n = 0; n < 8; ++n)
#pragma unroll
      for (int r = 0; r < 4; ++r)
        pgat[wave][lq * 4 + r][n * 16 + lm] = acc[n][r];
    __syncthreads();

    // ---- 7. cell math (2 cells/thread) + tagged publish ----
    {
      float hv0, hv1;
      unsigned pw0, pw1;
      const unsigned th = ((unsigned)(t + 1)) << 16;
#pragma unroll
      for (int j = 0; j < 2; ++j) {
        const int c = cpl + j;
        float iv = pgat[0][bl][c] + pgat[1][bl][c] +
                   pgat[2][bl][c] + pgat[3][bl][c];
        float fv = pgat[0][bl][32 + c] + pgat[1][bl][32 + c] +
                   pgat[2][bl][32 + c] + pgat[3][bl][32 + c];
        float gv = pgat[0][bl][64 + c] + pgat[1][bl][64 + c] +
                   pgat[2][bl][64 + c] + pgat[3][bl][64 + c];
        float o  = pgat[0][bl][96 + c] + pgat[1][bl][96 + c] +
                   pgat[2][bl][96 + c] + pgat[3][bl][96 + c];
        iv += (j ? bI.y : bI.x);
        fv += (j ? bF.y : bF.x);
        gv += (j ? bG.y : bG.x);
        o  += (j ? bO.y : bO.x);
        iv = 1.f / (1.f + __expf(-iv));
        fv = 1.f / (1.f + __expf(-fv));
        o  = 1.f / (1.f + __expf(-o));
        gv = 2.f / (1.f + __expf(-2.f * gv)) - 1.f;
        float cj = (j ? cc.y : cc.x);
        cj = fv * cj + iv * gv;
        const float thh = 2.f / (1.f + __expf(-2.f * cj)) - 1.f;
        const float hv = o * thh;
        BFU b_; b_.h = (__bf16)hv;
        if (j) { cc.y = cj; hv1 = hv; pw1 = th | (unsigned)b_.u; }
        else   { cc.x = cj; hv0 = hv; pw0 = th | (unsigned)b_.u; }
      }
      hl.x = hv0; hl.y = hv1;
      u32x2 pv; pv.x = pw0; pv.y = pw1;
      unsigned* pub = (t & 1) ? pub0 : pub1;   // step t -> slot (t+1)&1
      asm volatile("global_store_dwordx2 %0, %1, off sc0 sc1"
                   :: "v"(pub), "v"(pv) : "memory");
      // out[] store after publish: off the critical path
      float2 ov; ov.x = hv0; ov.y = hv1;
      *(float2*)(out + (size_t)gb * (SS * HH) + (size_t)t * HH + gcol) = ov;
    }
    __syncthreads();   // cell reads of pgat done before next step's writes
  }

  // ---- final h, c ----
  {
    const size_t OUTH = (size_t)BB * SS * HH;
    *(float2*)(out + OUTH + gb * HH + gcol) = hl;
    *(float2*)(out + OUTH + BB * HH + gb * HH + gcol) = cc;
  }
}

extern "C" void kernel_launch(void* const* d_in, const int* in_sizes, int n_in,
                              void* d_out, int out_size, void* d_ws, size_t ws_size,
                              hipStream_t stream) {
  const float* x    = (const float*)d_in[0];
  const float* h0   = (const float*)d_in[1];
  const float* c0   = (const float*)d_in[2];
  const float* W_ih = (const float*)d_in[3];
  const float* b_ih = (const float*)d_in[4];
  const float* W_hh = (const float*)d_in[5];
  float* out = (float*)d_out;

  // ws: tagged h words, 2 groups x 2 slots x 8192 u32 = 128KB. No flags.
  unsigned* hw = (unsigned*)d_ws;

  lstm_init<<<64, 256, 0, stream>>>(h0, hw);
  lstm_persistent<<<32, 256, 0, stream>>>(x, c0, W_ih, b_ih, W_hh, out, hw);
}

// Round 5
// 5502.432 us; speedup vs baseline: 3.2002x; 1.3560x over previous
//
#include <hip/hip_runtime.h>

// ManualLSTM: B=32, S=2048, I=256, H=512.
// Round-7: r6 (batch-grouped exchange, 7.34ms) + critical-path cleanup:
//   (1) x software-pipelined TWO steps ahead: raw float4 regs (xr) loaded one
//       full step before use, cvt->bf16 (xa) placed AFTER the h-MFMAs. r6 did
//       load+cvt between spin-exit and h-MFMA -- the cvt's implicit vmcnt wait
//       could put a ~900cy HBM RT on the per-step critical path.
//   (2) pgat double-buffered by step parity -> trailing barrier dropped
//       (WAR: step t+2 writes require passing barrier t+1, which all step-t
//       readers finished; one barrier per step).
//   (3) pgat row pad 132->133: cell reads 4-way -> 2-way bank conflict.
//   (4) v_rcp for sigmoid/tanh denominators (off the Newton-refined v_div).
// Structure (unchanged from r6, correctness-proven):
//   2 groups x 16 batches; 16 WGs/group each holding full W_hh for its 32
//   h-cols in VGPRs (128/lane); group-local tagged-word exchange
//   ((tag<<16)|bf16(h), 8B sc0 sc1 stores; slot parity; publish-certifies-
//   consumption induction covers slot WAR); speculative pulls + selective
//   per-chunk reload; x-part MFMA overlaps pull flight.

#define BB 32
#define SS 2048
#define II 256
#define HH 512
#define NT 256
#define SLOTW 8192              // words per group-slot: 16 batches x 512 cols

typedef __bf16 bf16x8 __attribute__((ext_vector_type(8)));
typedef float f32x4 __attribute__((ext_vector_type(4)));
typedef unsigned u32x4 __attribute__((ext_vector_type(4)));
typedef unsigned u32x2 __attribute__((ext_vector_type(2)));

union BFU { __bf16 h; unsigned short u; };
union FRG { unsigned d[4]; bf16x8 b; };

__device__ __forceinline__ bf16x8 cvt8(float4 a, float4 b) {
  bf16x8 r;
  r[0] = (__bf16)a.x; r[1] = (__bf16)a.y; r[2] = (__bf16)a.z; r[3] = (__bf16)a.w;
  r[4] = (__bf16)b.x; r[5] = (__bf16)b.y; r[6] = (__bf16)b.z; r[7] = (__bf16)b.w;
  return r;
}

__global__ __launch_bounds__(256, 1) void lstm_init(
    const float* __restrict__ h0, unsigned* __restrict__ hw) {
  int i = blockIdx.x * 256 + threadIdx.x;   // 0..16383 = B*H
  const int b = i >> 9, col = i & 511;
  const int G = b >> 4, bl = b & 15;
  BFU cv; cv.h = (__bf16)h0[i];
  hw[(G * 2 + 0) * SLOTW + bl * 512 + col] = (unsigned)cv.u;  // slot0: tag 0|h0
  hw[(G * 2 + 1) * SLOTW + bl * 512 + col] = 0xFFFF0000u;     // slot1: sentinel
}

__global__ __launch_bounds__(256, 1) void lstm_persistent(
    const float* __restrict__ x, const float* __restrict__ c0,
    const float* __restrict__ W_ih, const float* __restrict__ b_ih,
    const float* __restrict__ W_hh, float* __restrict__ out,
    unsigned* __restrict__ hw) {
  __shared__ __bf16 Wi[128][264];         // x-part weights: N=128 rows x 256 K
  __shared__ float pgat[2][4][16][133];   // DOUBLE-BUFFERED per-wave partials

  const int g = blockIdx.x;
  const int wgj = g & 15;              // col-slice within group
  const int grp = g >> 4;              // batch group (0/1)
  const int tid = threadIdx.x;
  const int wave = tid >> 6;
  const int lane = tid & 63;
  const int lm = lane & 15;            // batch row (M) / gate-col row (N)
  const int lq = lane >> 4;            // k-quarter within a 32-K tile

  // ---- stage W_ih slice into LDS as bf16 (once) ----
  for (int i = tid; i < 128 * II; i += NT) {
    const int row = i >> 8, k = i & 255;
    const int grow = (row >> 5) * HH + wgj * 32 + (row & 31);
    Wi[row][k] = (__bf16)W_ih[(size_t)grow * II + k];
  }

  // ---- W_hh fragments -> registers: wb[n][kt] (128 VGPR/lane) ----
  bf16x8 wb[8][4];
#pragma unroll
  for (int n = 0; n < 8; ++n) {
    const int localN = n * 16 + lm;
    const int grow = (localN >> 5) * HH + wgj * 32 + (localN & 31);
    const float* whr = W_hh + (size_t)grow * HH + wave * 128 + lq * 8;
#pragma unroll
    for (int kt = 0; kt < 4; ++kt)
      wb[n][kt] = cvt8(*(const float4*)(whr + kt * 32),
                       *(const float4*)(whr + kt * 32 + 4));
  }

  // ---- cell mapping: 256 threads x 2 cells (16 batches x 32 cols) ----
  const int bl = tid >> 4;             // local batch 0..15
  const int cpl = (tid & 15) * 2;      // even local h-col 0..30
  const int gb = grp * 16 + bl;        // global batch
  const int gcol = wgj * 32 + cpl;     // global h-col
  float2 cc, hl = make_float2(0.f, 0.f);
  float2 bI = *(const float2*)(b_ih + 0 * HH + gcol);
  float2 bF = *(const float2*)(b_ih + 1 * HH + gcol);
  float2 bG = *(const float2*)(b_ih + 2 * HH + gcol);
  float2 bO = *(const float2*)(b_ih + 3 * HH + gcol);
  cc = *(const float2*)(c0 + gb * HH + gcol);

  // ---- pointers ----
  unsigned* grpb = hw + grp * 2 * SLOTW;
  const char* pl0 = (const char*)(grpb + lm * 512 + wave * 128 + lq * 8);
  const char* pl1 = (const char*)(grpb + SLOTW + lm * 512 + wave * 128 + lq * 8);
  unsigned* pub0 = grpb + bl * 512 + gcol;
  unsigned* pub1 = grpb + SLOTW + bl * 512 + gcol;
  const float* xrow = x + (size_t)(grp * 16 + lm) * (SS * II) + wave * 64 + lq * 8;

  // ---- x pipeline: xa = converted frags for step t; xr = raw for t+1 ----
  float4 xr0, xr1, xr2, xr3;
  bf16x8 xa0, xa1;
#define XLOAD(T) { const float* xt_ = xrow + (size_t)(T) * II; \
  xr0 = *(const float4*)(xt_);      xr1 = *(const float4*)(xt_ + 4);  \
  xr2 = *(const float4*)(xt_ + 32); xr3 = *(const float4*)(xt_ + 36); }
#define XCVT() { xa0 = cvt8(xr0, xr1); xa1 = cvt8(xr2, xr3); }
  XLOAD(0) XCVT() XLOAD(1)

  __syncthreads();

#define LDC(Q, OFF) asm volatile( \
  "global_load_dwordx4 %0, %1, off offset:" #OFF " sc0 sc1" \
  : "=v"(Q) : "v"(pb) : "memory");
#define CK(Q, BIT) { if (((Q.x ^ etag) | (Q.z ^ etag)) & 0xFFFF0000u) \
  st |= BIT##u; }
#define RLD(Q, OFF, BIT) if (__any((int)(st & BIT##u))) { asm volatile( \
  "global_load_dwordx4 %0, %1, off offset:" #OFF " sc0 sc1" \
  : "=v"(Q) : "v"(pb) : "memory"); }
#define HSTEP(QA, QB, KT) { FRG u_; \
  u_.d[0] = __builtin_amdgcn_perm(QA.y, QA.x, 0x05040100u); \
  u_.d[1] = __builtin_amdgcn_perm(QA.w, QA.z, 0x05040100u); \
  u_.d[2] = __builtin_amdgcn_perm(QB.y, QB.x, 0x05040100u); \
  u_.d[3] = __builtin_amdgcn_perm(QB.w, QB.z, 0x05040100u); \
  _Pragma("unroll") \
  for (int n = 0; n < 8; ++n) \
    acc[n] = __builtin_amdgcn_mfma_f32_16x16x32_bf16(u_.b, wb[n][KT], \
                                                     acc[n], 0, 0, 0); }

  for (int t = 0; t < SS; ++t) {
    const unsigned etag = ((unsigned)t) << 16;
    const char* pb = (t & 1) ? pl1 : pl0;
    u32x4 q0, q1, q2, q3, q4, q5, q6, q7;

    // ---- 1. speculative pulls of this wave's K-quarter (8 x 16B) ----
    LDC(q0, 0)   LDC(q1, 16)  LDC(q2, 128) LDC(q3, 144)
    LDC(q4, 256) LDC(q5, 272) LDC(q6, 384) LDC(q7, 400)

    // ---- 2. x-part (overlaps pull flight): LDS weights, reg x-frags ----
    f32x4 acc[8] = {};
#pragma unroll
    for (int n = 0; n < 8; ++n) {
      const bf16x8 wib = *(const bf16x8*)(&Wi[n * 16 + lm][wave * 64 + lq * 8]);
      acc[n] = __builtin_amdgcn_mfma_f32_16x16x32_bf16(xa0, wib, acc[n], 0, 0, 0);
    }
#pragma unroll
    for (int n = 0; n < 8; ++n) {
      const bf16x8 wib =
          *(const bf16x8*)(&Wi[n * 16 + lm][wave * 64 + 32 + lq * 8]);
      acc[n] = __builtin_amdgcn_mfma_f32_16x16x32_bf16(xa1, wib, acc[n], 0, 0, 0);
    }

    // ---- 3. spin on data tags, selective per-chunk reload (fan = 16) ----
    for (;;) {
      asm volatile("s_waitcnt vmcnt(0)" ::: "memory");
      __builtin_amdgcn_sched_barrier(0);
      unsigned st = 0u;
      CK(q0, 0x1)  CK(q1, 0x2)  CK(q2, 0x4)  CK(q3, 0x8)
      CK(q4, 0x10) CK(q5, 0x20) CK(q6, 0x40) CK(q7, 0x80)
      if (__all((int)(st == 0u))) break;
      RLD(q0, 0, 0x1)    RLD(q1, 16, 0x2)
      RLD(q2, 128, 0x4)  RLD(q3, 144, 0x8)
      RLD(q4, 256, 0x10) RLD(q5, 272, 0x20)
      RLD(q6, 384, 0x40) RLD(q7, 400, 0x80)
    }

    // ---- 4. h-part: 4 K-tiles x 8 N-tiles of MFMA (pure reg operands) ----
    HSTEP(q0, q1, 0) HSTEP(q2, q3, 1) HSTEP(q4, q5, 2) HSTEP(q6, q7, 3)

    // ---- 5. x pipeline maintenance (OFF the critical path):
    //         xa <- cvt(xr) = x_{t+1};  xr <- raw x_{t+2} (flies ~1 step) ----
    XCVT()
    { const int tn = (t + 2 < SS) ? t + 2 : SS - 1; XLOAD(tn) }

    // ---- 6. per-wave partials -> LDS (parity buffer); ONE barrier ----
    // D layout: col = lane&15 (N within tile), row = lq*4 + r (M) [m89]
    float (*pg)[16][133] = pgat[t & 1];
#pragma unroll
    for (int n = 0; n < 8; ++n)
#pragma unroll
      for (int r = 0; r < 4; ++r)
        pg[wave][lq * 4 + r][n * 16 + lm] = acc[n][r];
    __syncthreads();

    // ---- 7. cell math (2 cells/thread) + tagged publish ----
    {
      float hv0, hv1;
      unsigned pw0, pw1;
      const unsigned th = ((unsigned)(t + 1)) << 16;
#pragma unroll
      for (int j = 0; j < 2; ++j) {
        const int c = cpl + j;
        float iv = pg[0][bl][c] + pg[1][bl][c] +
                   pg[2][bl][c] + pg[3][bl][c];
        float fv = pg[0][bl][32 + c] + pg[1][bl][32 + c] +
                   pg[2][bl][32 + c] + pg[3][bl][32 + c];
        float gv = pg[0][bl][64 + c] + pg[1][bl][64 + c] +
                   pg[2][bl][64 + c] + pg[3][bl][64 + c];
        float o  = pg[0][bl][96 + c] + pg[1][bl][96 + c] +
                   pg[2][bl][96 + c] + pg[3][bl][96 + c];
        iv += (j ? bI.y : bI.x);
        fv += (j ? bF.y : bF.x);
        gv += (j ? bG.y : bG.x);
        o  += (j ? bO.y : bO.x);
        iv = __builtin_amdgcn_rcpf(1.f + __expf(-iv));
        fv = __builtin_amdgcn_rcpf(1.f + __expf(-fv));
        o  = __builtin_amdgcn_rcpf(1.f + __expf(-o));
        gv = 2.f * __builtin_amdgcn_rcpf(1.f + __expf(-2.f * gv)) - 1.f;
        float cj = (j ? cc.y : cc.x);
        cj = fv * cj + iv * gv;
        const float thh =
            2.f * __builtin_amdgcn_rcpf(1.f + __expf(-2.f * cj)) - 1.f;
        const float hv = o * thh;
        BFU b_; b_.h = (__bf16)hv;
        if (j) { cc.y = cj; hv1 = hv; pw1 = th | (unsigned)b_.u; }
        else   { cc.x = cj; hv0 = hv; pw0 = th | (unsigned)b_.u; }
      }
      hl.x = hv0; hl.y = hv1;
      u32x2 pv; pv.x = pw0; pv.y = pw1;
      unsigned* pub = (t & 1) ? pub0 : pub1;   // step t -> slot (t+1)&1
      asm volatile("global_store_dwordx2 %0, %1, off sc0 sc1"
                   :: "v"(pub), "v"(pv) : "memory");
      // out[] store after publish: off the critical path
      float2 ov; ov.x = hv0; ov.y = hv1;
      *(float2*)(out + (size_t)gb * (SS * HH) + (size_t)t * HH + gcol) = ov;
    }
    // no trailing barrier: pgat is parity-double-buffered; step t+2 writes to
    // this buffer require passing the (t+1) barrier, which all readers of
    // step t have already finished.
  }

  // ---- final h, c ----
  {
    const size_t OUTH = (size_t)BB * SS * HH;
    *(float2*)(out + OUTH + gb * HH + gcol) = hl;
    *(float2*)(out + OUTH + BB * HH + gb * HH + gcol) = cc;
  }
}

extern "C" void kernel_launch(void* const* d_in, const int* in_sizes, int n_in,
                              void* d_out, int out_size, void* d_ws, size_t ws_size,
                              hipStream_t stream) {
  const float* x    = (const float*)d_in[0];
  const float* h0   = (const float*)d_in[1];
  const float* c0   = (const float*)d_in[2];
  const float* W_ih = (const float*)d_in[3];
  const float* b_ih = (const float*)d_in[4];
  const float* W_hh = (const float*)d_in[5];
  float* out = (float*)d_out;

  // ws: tagged h words, 2 groups x 2 slots x 8192 u32 = 128KB. No flags.
  unsigned* hw = (unsigned*)d_ws;

  lstm_init<<<64, 256, 0, stream>>>(h0, hw);
  lstm_persistent<<<32, 256, 0, stream>>>(x, c0, W_ih, b_ih, W_hh, out, hw);
}